// Round 1
// baseline (4913.215 us; speedup 1.0000x reference)
//
#include <hip/hip_runtime.h>
#include <hip/hip_bf16.h>

using bf16 = __hip_bfloat16;
typedef __attribute__((ext_vector_type(8))) short bf16x8;
typedef __attribute__((ext_vector_type(4))) float f32x4;

static constexpr int HD = 2048;   // hidden
static constexpr int BB = 512;    // batch
static constexpr int OD = 512;    // output dim
static constexpr int TT = 32;     // time steps

#define MFMA(a, b, c) __builtin_amdgcn_mfma_f32_16x16x32_bf16((a), (b), (c), 0, 0, 0)

__device__ __forceinline__ void gld16(const void* g, void* l) {
  __builtin_amdgcn_global_load_lds((const __attribute__((address_space(1))) void*)g,
                                   (__attribute__((address_space(3))) void*)l, 16, 0, 0);
}

// one-time fp32 -> bf16 conversion
__global__ __launch_bounds__(256) void cvt_kernel(const float* __restrict__ s,
                                                  bf16* __restrict__ d, int n4) {
  const int i = blockIdx.x * 256 + threadIdx.x;
  if (i < n4) {
    const float4 v = ((const float4*)s)[i];
    union { unsigned long long u; bf16 e[4]; } o;
    o.e[0] = __float2bfloat16(v.x); o.e[1] = __float2bfloat16(v.y);
    o.e[2] = __float2bfloat16(v.z); o.e[3] = __float2bfloat16(v.w);
    *(unsigned long long*)(d + 4l * i) = o.u;
  }
}

// Fused GRU cell. Block: 128m x 32n x 3 gates, 4 waves; wave = 64m x 16n x 3
// (12 MFMA, 7 ds_read_b128 per K-step).
// Depth-3 counted-vmcnt pipeline: 5 LDS buffers; stage(s+3) issued while
// computing s; per K-step one raw {s_waitcnt vmcnt(2n); s_barrier} (n = own
// DMA issues/slice: A-waves 4 -> vmcnt(8), W-waves 3 -> vmcnt(6)); fragments
// for s+1 are ds_read into the idle regset before the MFMAs of s (manual 2x
// unroll, named regsets -- no runtime-indexed frag arrays).
// LDS 16B-column XOR swizzle c^=( (row>>1)&3 ): gld16 dest stays linear,
// global source column pre-swizzled (slc), reads swizzled (sq16).
#define CELL_WB                                                                \
  { if (w < 2) asm volatile("s_waitcnt vmcnt(8)\n\ts_barrier" ::: "memory");   \
    else       asm volatile("s_waitcnt vmcnt(6)\n\ts_barrier" ::: "memory"); }

__global__ __launch_bounds__(256) void gru_cell_kernel(
    const bf16* __restrict__ Ax, int Kx,        // [B, Kx] bf16 layer input
    const bf16* __restrict__ Ahb,               // [B, H] bf16 h shadow
    const float* __restrict__ hprevf,           // [B, H] fp32 h master
    const bf16* __restrict__ Wih,               // [3H, Kx] bf16
    const bf16* __restrict__ Whh,               // [3H, H] bf16
    const float* __restrict__ bih, const float* __restrict__ bhh,
    float* __restrict__ houtf, bf16* __restrict__ houtb) {
  __shared__ __align__(1024) char smem[5 * 14336];  // [A 8KB | W 6KB] x 5
  const int tid = threadIdx.x;
  const int lane = tid & 63;
  const int w = __builtin_amdgcn_readfirstlane(tid >> 6);
  const int wm = w >> 1, wn = w & 1;
  const int bid = blockIdx.x;
  const int rest = bid >> 3;
  const int m0 = (rest >> 3) * 128;               // 4 m-groups
  const int n0 = ((bid & 7) * 8 + (rest & 7)) * 32;  // same-n -> same XCD
  const int lr = lane >> 2;
  const int slc = (((lane & 3) ^ ((lr >> 1) & 3)) << 3);  // swizzled src k-off
  const int cl = lane & 15, q = lane >> 4;
  const int sq16 = ((q ^ ((cl >> 1) & 3)) << 4);          // swizzled read 16B col
  const int nsa = Kx >> 5, nsb = HD >> 5, ns = nsa + nsb;

  const int aOff = (wm * 64 + cl) * 64 + sq16;
  const int wOff = 8192 + (wn * 16 + cl) * 64 + sq16;

  // acc: 0=r, 1=z (both phases), 2=gx_n (A), 3=gh_n (B); [gate][m-frag]
  f32x4 acc[4][4];
#pragma unroll
  for (int a = 0; a < 4; ++a)
#pragma unroll
    for (int i = 0; i < 4; ++i) acc[a][i] = (f32x4){0.f, 0.f, 0.f, 0.f};

  // stage K-slice s (global index over both phases) into buffer at base.
  // waves 0-1: A (4 issues, 16 rows x 64B each); waves 2-3: W (3 issues each).
  auto stageS = [&](int s, char* base) {
    const bf16* Ap; const bf16* Wp; int K; int ss;
    if (s < nsa) { Ap = Ax;  Wp = Wih; K = Kx; ss = s; }
    else         { Ap = Ahb; Wp = Whh; K = HD; ss = s - nsa; }
    const int k0 = (ss << 5) + slc;
    if (w < 2) {
#pragma unroll
      for (int it = 0; it < 4; ++it) {
        const int r = (w * 4 + it) * 16;
        gld16(Ap + (long)(m0 + r + lr) * K + k0, base + r * 64);
      }
    } else {
#pragma unroll
      for (int it = 0; it < 3; ++it) {
        const int jj = (w - 2) * 3 + it;       // 0..5: gate jj>>1, half jj&1
        gld16(Wp + ((long)(jj >> 1) * HD + n0 + (jj & 1) * 16 + lr) * K + k0,
              base + 8192 + jj * 1024);
      }
    }
  };

  char* const s_end = smem + 5 * 14336;
  auto adv = [&](char*& p) { p += 14336; if (p == s_end) p = smem; };

  bf16x8 fa0, fa1, fa2, fa3, fw0, fw1, fw2;   // regset f
  bf16x8 ga0, ga1, ga2, ga3, gw0, gw1, gw2;   // regset g

#define LOADF(P, B)                                                            \
  {                                                                            \
    const char* a_ = (B) + aOff; const char* w_ = (B) + wOff;                  \
    P##a0 = *(const bf16x8*)(a_);        P##a1 = *(const bf16x8*)(a_ + 1024);  \
    P##a2 = *(const bf16x8*)(a_ + 2048); P##a3 = *(const bf16x8*)(a_ + 3072);  \
    P##w0 = *(const bf16x8*)(w_);        P##w1 = *(const bf16x8*)(w_ + 2048);  \
    P##w2 = *(const bf16x8*)(w_ + 4096);                                       \
  }

#define MFMAS(P, NACC)                                                         \
  {                                                                            \
    acc[0][0] = MFMA(P##a0, P##w0, acc[0][0]);                                 \
    acc[0][1] = MFMA(P##a1, P##w0, acc[0][1]);                                 \
    acc[0][2] = MFMA(P##a2, P##w0, acc[0][2]);                                 \
    acc[0][3] = MFMA(P##a3, P##w0, acc[0][3]);                                 \
    acc[1][0] = MFMA(P##a0, P##w1, acc[1][0]);                                 \
    acc[1][1] = MFMA(P##a1, P##w1, acc[1][1]);                                 \
    acc[1][2] = MFMA(P##a2, P##w1, acc[1][2]);                                 \
    acc[1][3] = MFMA(P##a3, P##w1, acc[1][3]);                                 \
    acc[NACC][0] = MFMA(P##a0, P##w2, acc[NACC][0]);                           \
    acc[NACC][1] = MFMA(P##a1, P##w2, acc[NACC][1]);                           \
    acc[NACC][2] = MFMA(P##a2, P##w2, acc[NACC][2]);                           \
    acc[NACC][3] = MFMA(P##a3, P##w2, acc[NACC][3]);                           \
  }

// one 2-step pair: compute s (regset f) + s+1 (regset g), prefetch frags
// for s+1 / s+2 into the idle regset; stage slices s+3 / s+4 (clamped).
#define CELL_PAIR(NACC)                                                        \
  {                                                                            \
    stageS(s + 3 < ns ? s + 3 : ns - 1, sb); adv(sb);                          \
    CELL_WB;                                                                   \
    LOADF(g, rb); adv(rb);                                                     \
    MFMAS(f, NACC);                                                            \
    stageS(s + 4 < ns ? s + 4 : ns - 1, sb); adv(sb);                          \
    CELL_WB;                                                                   \
    if (s + 2 < ns) LOADF(f, rb);                                              \
    adv(rb);                                                                   \
    MFMAS(g, NACC);                                                            \
  }

  stageS(0, smem);
  stageS(1, smem + 14336);
  stageS(2, smem + 2 * 14336);
  char* sb = smem + 3 * 14336;
  char* rb = smem;
  CELL_WB;                       // slice 0 resident for all waves
  LOADF(f, rb); adv(rb);

  int s = 0;
  for (; s < nsa; s += 2) CELL_PAIR(2);   // phase A: x @ Wih^T (nsa even)
  for (; s < ns; s += 2) CELL_PAIR(3);    // phase B: h @ Whh^T

  // C/D layout: col=lane&15, row=(lane>>4)*4+reg (m89-verified)
  const int j = n0 + wn * 16 + cl;
  const float bihr = bih[j], bihz = bih[j + HD], bihn = bih[j + 2 * HD];
  const float bhhr = bhh[j], bhhz = bhh[j + HD], bhhn = bhh[j + 2 * HD];
#pragma unroll
  for (int mi = 0; mi < 4; ++mi)
#pragma unroll
    for (int r = 0; r < 4; ++r) {
      const int b = m0 + wm * 64 + mi * 16 + q * 4 + r;
      const float gr = acc[0][mi][r] + bihr + bhhr;
      const float gz = acc[1][mi][r] + bihz + bhhz;
      const float gnx = acc[2][mi][r] + bihn;
      const float gnh = acc[3][mi][r] + bhhn;
      const float rr = 1.f / (1.f + __expf(-gr));
      const float zz = 1.f / (1.f + __expf(-gz));
      const float nn = tanhf(gnx + rr * gnh);
      const float hp = hprevf[(long)b * HD + j];
      const float hn = (1.f - zz) * nn + zz * hp;
      houtf[(long)b * HD + j] = hn;
      houtb[(long)b * HD + j] = __float2bfloat16(hn);
    }
}

// C = A @ W^T + bias, tile 64m x 64n, 4 waves (wave = 64m x 16n), same
// depth-3 counted-vmcnt pipeline (2 issues/wave/slice -> vmcnt(4)).
// mode 0: embedding — relu, scatter rows (b*2+l) into h0/h1 (fp32+bf16)
// mode 1: projection — preds[b,t,:] fp32 + xbuf bf16
#define G64_WB asm volatile("s_waitcnt vmcnt(4)\n\ts_barrier" ::: "memory");

__global__ __launch_bounds__(256) void gemm64_kernel(
    const bf16* __restrict__ A, const bf16* __restrict__ W,
    const float* __restrict__ bias, int K, int mode, int t, int nbits,
    float* __restrict__ o0f, bf16* __restrict__ o0b,
    float* __restrict__ o1f, bf16* __restrict__ o1b,
    float* __restrict__ preds, bf16* __restrict__ xbuf) {
  __shared__ __align__(1024) char smem[5 * 8192];  // [A 4KB | W 4KB] x 5
  const int tid = threadIdx.x;
  const int lane = tid & 63;
  const int w = __builtin_amdgcn_readfirstlane(tid >> 6);
  const int bid = blockIdx.x;
  const int rest = bid >> 3;
  const int m0 = (rest >> nbits) * 64;
  const int n0 = (((bid & 7) << nbits) + (rest & ((1 << nbits) - 1))) * 64;
  const int lr = lane >> 2;
  const int slc = (((lane & 3) ^ ((lr >> 1) & 3)) << 3);
  const int cl = lane & 15, q = lane >> 4;
  const int sq16 = ((q ^ ((cl >> 1) & 3)) << 4);
  const int ns = K >> 5;

  const int aOff = cl * 64 + sq16;
  const int wOff = 4096 + (w * 16 + cl) * 64 + sq16;

  f32x4 acc[4];
#pragma unroll
  for (int i = 0; i < 4; ++i) acc[i] = (f32x4){0.f, 0.f, 0.f, 0.f};

  auto stageS = [&](int s, char* base) {
    const int k0 = (s << 5) + slc;
    if (w < 2) {
#pragma unroll
      for (int it = 0; it < 2; ++it) {
        const int r = (w * 2 + it) * 16;
        gld16(A + (long)(m0 + r + lr) * K + k0, base + r * 64);
      }
    } else {
#pragma unroll
      for (int it = 0; it < 2; ++it) {
        const int jj = (w - 2) * 2 + it;       // 0..3
        gld16(W + (long)(n0 + jj * 16 + lr) * K + k0, base + 4096 + jj * 1024);
      }
    }
  };

  char* const s_end = smem + 5 * 8192;
  auto adv = [&](char*& p) { p += 8192; if (p == s_end) p = smem; };

  bf16x8 fa0, fa1, fa2, fa3, fw;
  bf16x8 ga0, ga1, ga2, ga3, gw;

#define G64_LOADF(P, B)                                                        \
  {                                                                            \
    const char* a_ = (B) + aOff;                                               \
    P##a0 = *(const bf16x8*)(a_);        P##a1 = *(const bf16x8*)(a_ + 1024);  \
    P##a2 = *(const bf16x8*)(a_ + 2048); P##a3 = *(const bf16x8*)(a_ + 3072);  \
    P##w = *(const bf16x8*)((B) + wOff);                                       \
  }

#define G64_MFMAS(P)                                                           \
  {                                                                            \
    acc[0] = MFMA(P##a0, P##w, acc[0]);                                        \
    acc[1] = MFMA(P##a1, P##w, acc[1]);                                        \
    acc[2] = MFMA(P##a2, P##w, acc[2]);                                        \
    acc[3] = MFMA(P##a3, P##w, acc[3]);                                        \
  }

  stageS(0, smem);
  stageS(1, smem + 8192);
  stageS(2, smem + 2 * 8192);
  char* sb = smem + 3 * 8192;
  char* rb = smem;
  G64_WB;
  G64_LOADF(f, rb); adv(rb);

  for (int s = 0; s < ns; s += 2) {
    stageS(s + 3 < ns ? s + 3 : ns - 1, sb); adv(sb);
    G64_WB;
    G64_LOADF(g, rb); adv(rb);
    G64_MFMAS(f);
    stageS(s + 4 < ns ? s + 4 : ns - 1, sb); adv(sb);
    G64_WB;
    if (s + 2 < ns) G64_LOADF(f, rb);
    adv(rb);
    G64_MFMAS(g);
  }

  const int j = n0 + w * 16 + cl;
  const float bj = bias[j];
#pragma unroll
  for (int mi = 0; mi < 4; ++mi)
#pragma unroll
    for (int r = 0; r < 4; ++r) {
      const int row = m0 + mi * 16 + q * 4 + r;
      float v = acc[mi][r] + bj;
      if (mode == 0) {
        v = fmaxf(v, 0.f);
        const int b = row >> 1, l = row & 1;   // x rows are (b, l) pairs
        if (l == 0) { o0f[(long)b * HD + j] = v; o0b[(long)b * HD + j] = __float2bfloat16(v); }
        else        { o1f[(long)b * HD + j] = v; o1b[(long)b * HD + j] = __float2bfloat16(v); }
      } else {
        preds[((long)row * TT + t) * OD + j] = v;
        xbuf[(long)row * OD + j] = __float2bfloat16(v);
      }
    }
}

// ---- naive fallbacks (only if workspace too small for bf16 weights) ----
__global__ __launch_bounds__(256) void gru_cell_naive(
    const bf16* __restrict__ Ax, int Kx, const bf16* __restrict__ Ahb,
    const float* __restrict__ hprevf,
    const float* __restrict__ Wih, const float* __restrict__ Whh,
    const float* __restrict__ bih, const float* __restrict__ bhh,
    float* __restrict__ houtf, bf16* __restrict__ houtb) {
  const int idx = blockIdx.x * 256 + threadIdx.x;
  if (idx >= BB * HD) return;
  const int b = idx / HD, j = idx % HD;
  float gr = bih[j] + bhh[j], gz = bih[j + HD] + bhh[j + HD];
  float gnx = bih[j + 2 * HD], gnh = bhh[j + 2 * HD];
  for (int k = 0; k < Kx; ++k) {
    const float xv = __bfloat162float(Ax[(long)b * Kx + k]);
    gr += xv * Wih[(long)j * Kx + k];
    gz += xv * Wih[((long)j + HD) * Kx + k];
    gnx += xv * Wih[((long)j + 2 * HD) * Kx + k];
  }
  for (int k = 0; k < HD; ++k) {
    const float hv = __bfloat162float(Ahb[(long)b * HD + k]);
    gr += hv * Whh[(long)j * HD + k];
    gz += hv * Whh[((long)j + HD) * HD + k];
    gnh += hv * Whh[((long)j + 2 * HD) * HD + k];
  }
  const float rr = 1.f / (1.f + __expf(-gr));
  const float zz = 1.f / (1.f + __expf(-gz));
  const float nn = tanhf(gnx + rr * gnh);
  const float hp = hprevf[(long)b * HD + j];
  const float hn = (1.f - zz) * nn + zz * hp;
  houtf[(long)b * HD + j] = hn;
  houtb[(long)b * HD + j] = __float2bfloat16(hn);
}

__global__ __launch_bounds__(256) void naive_gemm(
    const void* __restrict__ A, int abf, const float* __restrict__ W,
    const float* __restrict__ bias, int N, int K, int mode, int t,
    float* __restrict__ o0f, bf16* __restrict__ o0b,
    float* __restrict__ o1f, bf16* __restrict__ o1b,
    float* __restrict__ preds, bf16* __restrict__ xbuf) {
  const long idx = (long)blockIdx.x * 256 + threadIdx.x;
  const int row = idx / N, j = idx % N;
  float v = bias[j];
  for (int k = 0; k < K; ++k) {
    const float av = abf ? __bfloat162float(((const bf16*)A)[(long)row * K + k])
                         : ((const float*)A)[(long)row * K + k];
    v += av * W[(long)j * K + k];
  }
  if (mode == 0) {
    v = fmaxf(v, 0.f);
    const int b = row >> 1, l = row & 1;
    if (l == 0) { o0f[(long)b * HD + j] = v; o0b[(long)b * HD + j] = __float2bfloat16(v); }
    else        { o1f[(long)b * HD + j] = v; o1b[(long)b * HD + j] = __float2bfloat16(v); }
  } else {
    preds[((long)row * TT + t) * OD + j] = v;
    xbuf[(long)row * OD + j] = __float2bfloat16(v);
  }
}

extern "C" void kernel_launch(void* const* d_in, const int* in_sizes, int n_in,
                              void* d_out, int out_size, void* d_ws, size_t ws_size,
                              hipStream_t stream) {
  const float* x    = (const float*)d_in[0];
  const float* embW = (const float*)d_in[1];
  const float* embb = (const float*)d_in[2];
  const float* Wih0 = (const float*)d_in[3];
  const float* Whh0 = (const float*)d_in[4];
  const float* bih0 = (const float*)d_in[5];
  const float* bhh0 = (const float*)d_in[6];
  const float* Wih1 = (const float*)d_in[7];
  const float* Whh1 = (const float*)d_in[8];
  const float* bih1 = (const float*)d_in[9];
  const float* bhh1 = (const float*)d_in[10];
  const float* outW = (const float*)d_in[11];
  const float* outb = (const float*)d_in[12];
  float* preds = (float*)d_out;

  char* p = (char*)d_ws;
  const size_t HF = (size_t)BB * HD * 4;
  const size_t HB = (size_t)BB * HD * 2;
  float* h0f[2] = {(float*)p, (float*)(p + HF)}; p += 2 * HF;
  float* h1f[2] = {(float*)p, (float*)(p + HF)}; p += 2 * HF;
  bf16* h0b[2] = {(bf16*)p, (bf16*)(p + HB)}; p += 2 * HB;
  bf16* h1b[2] = {(bf16*)p, (bf16*)(p + HB)}; p += 2 * HB;
  bf16* xbuf = (bf16*)p; p += (size_t)BB * OD * 2;

  const int nE = 2048 * 1024, nI0 = 6144 * 512, nH = 6144 * 2048,
            nO = 512 * 2048, nX = 1024 * 1024;
  const size_t conv_bytes = 2ul * (nE + nI0 + 3ul * nH + nO + nX);
  const bool big = ws_size >= (size_t)(p - (char*)d_ws) + conv_bytes;

  hipMemsetAsync(xbuf, 0, (size_t)BB * OD * 2, stream);  // zero input, steps 0-1

  if (big) {
    bf16* embWc = (bf16*)p; p += 2ul * nE;
    bf16* Wih0c = (bf16*)p; p += 2ul * nI0;
    bf16* Whh0c = (bf16*)p; p += 2ul * nH;
    bf16* Wih1c = (bf16*)p; p += 2ul * nH;
    bf16* Whh1c = (bf16*)p; p += 2ul * nH;
    bf16* outWc = (bf16*)p; p += 2ul * nO;
    bf16* xbf   = (bf16*)p; p += 2ul * nX;
    auto cv = [&](const float* s, bf16* d, int n) {
      cvt_kernel<<<(n / 4 + 255) / 256, 256, 0, stream>>>(s, d, n / 4);
    };
    cv(embW, embWc, nE); cv(Wih0, Wih0c, nI0); cv(Whh0, Whh0c, nH);
    cv(Wih1, Wih1c, nH); cv(Whh1, Whh1c, nH); cv(outW, outWc, nO);
    cv(x, xbf, nX);

    // embedding: xbf [1024,1024] -> h0/h1; 16 m-tiles x 32 n-tiles
    gemm64_kernel<<<512, 256, 0, stream>>>(
        xbf, embWc, embb, 1024, 0, 0, 2,
        h0f[0], h0b[0], h1f[0], h1b[0], nullptr, nullptr);

    for (int s = 0; s < 33; ++s) {
      const int cur = s & 1, nxt = cur ^ 1;
      gru_cell_kernel<<<256, 256, 0, stream>>>(
          xbuf, OD, h0b[cur], h0f[cur], Wih0c, Whh0c, bih0, bhh0,
          h0f[nxt], h0b[nxt]);
      gru_cell_kernel<<<256, 256, 0, stream>>>(
          h0b[nxt], HD, h1b[cur], h1f[cur], Wih1c, Whh1c, bih1, bhh1,
          h1f[nxt], h1b[nxt]);
      if (s >= 1)
        gemm64_kernel<<<64, 256, 0, stream>>>(
            h1b[nxt], outWc, outb, HD, 1, s - 1, 0,
            nullptr, nullptr, nullptr, nullptr, preds, xbuf);
    }
  } else {
    naive_gemm<<<(1024 * 2048) / 256, 256, 0, stream>>>(
        x, 0, embW, embb, 2048, 1024, 0, 0,
        h0f[0], h0b[0], h1f[0], h1b[0], nullptr, nullptr);
    for (int s = 0; s < 33; ++s) {
      const int cur = s & 1, nxt = cur ^ 1;
      gru_cell_naive<<<(BB * HD + 255) / 256, 256, 0, stream>>>(
          xbuf, OD, h0b[cur], h0f[cur], Wih0, Whh0, bih0, bhh0,
          h0f[nxt], h0b[nxt]);
      gru_cell_naive<<<(BB * HD + 255) / 256, 256, 0, stream>>>(
          h0b[nxt], HD, h1b[cur], h1f[cur], Wih1, Whh1, bih1, bhh1,
          h1f[nxt], h1b[nxt]);
      if (s >= 1)
        naive_gemm<<<(512 * 512) / 256, 256, 0, stream>>>(
            h1b[nxt], 1, outW, outb, 512, 2048, 1, s - 1,
            nullptr, nullptr, nullptr, nullptr, preds, xbuf);
    }
  }
}

// Round 2
// 3610.316 us; speedup vs baseline: 1.3609x; 1.3609x over previous
//
#include <hip/hip_runtime.h>
#include <hip/hip_bf16.h>

using bf16 = __hip_bfloat16;
typedef __attribute__((ext_vector_type(8))) short bf16x8;
typedef __attribute__((ext_vector_type(4))) float f32x4;

static constexpr int HD = 2048;   // hidden
static constexpr int BB = 512;    // batch
static constexpr int OD = 512;    // output dim
static constexpr int TT = 32;     // time steps

#define MFMA(a, b, c) __builtin_amdgcn_mfma_f32_16x16x32_bf16((a), (b), (c), 0, 0, 0)

__device__ __forceinline__ void gld16(const void* g, void* l) {
  __builtin_amdgcn_global_load_lds((const __attribute__((address_space(1))) void*)g,
                                   (__attribute__((address_space(3))) void*)l, 16, 0, 0);
}

// one-time fp32 -> bf16 conversion
__global__ __launch_bounds__(256) void cvt_kernel(const float* __restrict__ s,
                                                  bf16* __restrict__ d, int n4) {
  const int i = blockIdx.x * 256 + threadIdx.x;
  if (i < n4) {
    const float4 v = ((const float4*)s)[i];
    union { unsigned long long u; bf16 e[4]; } o;
    o.e[0] = __float2bfloat16(v.x); o.e[1] = __float2bfloat16(v.y);
    o.e[2] = __float2bfloat16(v.z); o.e[3] = __float2bfloat16(v.w);
    *(unsigned long long*)(d + 4l * i) = o.u;
  }
}

// Fused GRU cell, round-0 single-barrier dbuf schedule (proven fastest),
// plus LDS XOR swizzle (bank conflicts 3.67M -> 0, round-1 verified), plus
// 2x occupancy: m-tile 64 -> grid 512 = 2 blocks/CU = 2 waves/SIMD so one
// block's MFMAs overlap the other's barrier drain.
// Block: 64m x 32n x 3 gates, 4 waves; wave = 32m x 16n x 3 gates
// (6 MFMA, 5 ds_read_b128 per K-step). LDS dbuf 2 x 10KB (A 4KB | W 6KB).
// Swizzle: LDS 16B-col c holds global k-chunk c ^ ((row%16)>>1 & 3); gld16
// dest stays linear (rule 21), global source column pre-swizzled (slc),
// reads swizzled (sq16).
#define CELL_STEP(NACC, STAGE_CALL)                                            \
  {                                                                            \
    __syncthreads();                                                           \
    STAGE_CALL;                                                                \
    const char* base = smem + buf * 10240;                                     \
    const char* aB = base + (wm * 32 + cl) * 64 + sq16;                        \
    const char* wB = base + 4096 + (wn * 16 + cl) * 64 + sq16;                 \
    bf16x8 a0 = *(const bf16x8*)(aB);                                          \
    bf16x8 a1 = *(const bf16x8*)(aB + 1024);                                   \
    bf16x8 w0 = *(const bf16x8*)(wB);                                          \
    bf16x8 w1 = *(const bf16x8*)(wB + 2048);                                   \
    bf16x8 w2 = *(const bf16x8*)(wB + 4096);                                   \
    acc[0][0] = MFMA(a0, w0, acc[0][0]);                                       \
    acc[0][1] = MFMA(a1, w0, acc[0][1]);                                       \
    acc[1][0] = MFMA(a0, w1, acc[1][0]);                                       \
    acc[1][1] = MFMA(a1, w1, acc[1][1]);                                       \
    acc[NACC][0] = MFMA(a0, w2, acc[NACC][0]);                                 \
    acc[NACC][1] = MFMA(a1, w2, acc[NACC][1]);                                 \
    buf ^= 1;                                                                  \
  }

__global__ __launch_bounds__(256) void gru_cell_kernel(
    const bf16* __restrict__ Ax, int Kx,        // [B, Kx] bf16 layer input
    const bf16* __restrict__ Ahb,               // [B, H] bf16 h shadow
    const float* __restrict__ hprevf,           // [B, H] fp32 h master
    const bf16* __restrict__ Wih,               // [3H, Kx] bf16
    const bf16* __restrict__ Whh,               // [3H, H] bf16
    const float* __restrict__ bih, const float* __restrict__ bhh,
    float* __restrict__ houtf, bf16* __restrict__ houtb) {
  __shared__ __align__(1024) char smem[2 * 10240];  // [A 4KB | W 6KB] x 2
  const int tid = threadIdx.x;
  const int lane = tid & 63;
  const int w = __builtin_amdgcn_readfirstlane(tid >> 6);
  const int wm = w >> 1, wn = w & 1;
  const int bid = blockIdx.x;
  const int rest = bid >> 3;
  const int m0 = (rest >> 3) * 64;                // 8 m-groups
  const int n0 = ((bid & 7) * 8 + (rest & 7)) * 32;  // same-n -> same XCD
  const int lr = lane >> 2;
  const int slc = (((lane & 3) ^ ((lr >> 1) & 3)) << 3);  // swizzled src k-off
  const int cl = lane & 15, q = lane >> 4;
  const int sq16 = ((q ^ ((cl >> 1) & 3)) << 4);          // swizzled read col
  const int nsa = Kx >> 5, nsb = HD >> 5;

  // acc: 0=r, 1=z (both phases), 2=gx_n (A), 3=gh_n (B); [gate][m-frag]
  f32x4 acc[4][2];
#pragma unroll
  for (int a = 0; a < 4; ++a)
#pragma unroll
    for (int i = 0; i < 2; ++i) acc[a][i] = (f32x4){0.f, 0.f, 0.f, 0.f};

  // stage K-slice s of (Ap,Wp) into buffer b. waves 0-1: A (2 issues each,
  // 16 rows x 64B = 1KB contiguous per issue); waves 2-3: W (3 issues each).
  auto stage = [&](const bf16* Ap, const bf16* Wp, int K, int s, int b) {
    char* base = smem + b * 10240;
    const int k0 = (s << 5) + slc;
    if (w < 2) {
#pragma unroll
      for (int it = 0; it < 2; ++it) {
        const int r = (w * 2 + it) * 16;
        gld16(Ap + (long)(m0 + r + lr) * K + k0, base + r * 64);
      }
    } else {
#pragma unroll
      for (int it = 0; it < 3; ++it) {
        const int jj = (w - 2) * 3 + it;       // 0..5: gate jj>>1, half jj&1
        gld16(Wp + ((long)(jj >> 1) * HD + n0 + (jj & 1) * 16 + lr) * K + k0,
              base + 4096 + jj * 1024);
      }
    }
  };

  stage(Ax, Wih, Kx, 0, 0);
  int buf = 0;
  for (int s = 0; s < nsa; ++s)                  // phase A: x @ Wih^T
    CELL_STEP(2, if (s + 1 < nsa) stage(Ax, Wih, Kx, s + 1, buf ^ 1);
                 else stage(Ahb, Whh, HD, 0, buf ^ 1));
  for (int s = 0; s < nsb; ++s)                  // phase B: h @ Whh^T
    CELL_STEP(3, if (s + 1 < nsb) stage(Ahb, Whh, HD, s + 1, buf ^ 1));

  // C/D layout: col=lane&15, row=(lane>>4)*4+reg (m89-verified)
  const int j = n0 + wn * 16 + cl;
  const float bihr = bih[j], bihz = bih[j + HD], bihn = bih[j + 2 * HD];
  const float bhhr = bhh[j], bhhz = bhh[j + HD], bhhn = bhh[j + 2 * HD];
#pragma unroll
  for (int mi = 0; mi < 2; ++mi)
#pragma unroll
    for (int r = 0; r < 4; ++r) {
      const int b = m0 + wm * 32 + mi * 16 + q * 4 + r;
      const float gr = acc[0][mi][r] + bihr + bhhr;
      const float gz = acc[1][mi][r] + bihz + bhhz;
      const float gnx = acc[2][mi][r] + bihn;
      const float gnh = acc[3][mi][r] + bhhn;
      const float rr = 1.f / (1.f + __expf(-gr));
      const float zz = 1.f / (1.f + __expf(-gz));
      const float nn = tanhf(gnx + rr * gnh);
      const float hp = hprevf[(long)b * HD + j];
      const float hn = (1.f - zz) * nn + zz * hp;
      houtf[(long)b * HD + j] = hn;
      houtb[(long)b * HD + j] = __float2bfloat16(hn);
    }
}

// C = A @ W^T + bias, tile 64m x 64n, 4 waves (wave = 64m x 16n), round-0
// single-barrier dbuf + LDS swizzle. A,W bf16.
// mode 0: embedding — relu, scatter rows (b*2+l) into h0/h1 (fp32+bf16)
// mode 1: projection — preds[b,t,:] fp32 + xbuf bf16
__global__ __launch_bounds__(256) void gemm64_kernel(
    const bf16* __restrict__ A, const bf16* __restrict__ W,
    const float* __restrict__ bias, int K, int mode, int t, int nbits,
    float* __restrict__ o0f, bf16* __restrict__ o0b,
    float* __restrict__ o1f, bf16* __restrict__ o1b,
    float* __restrict__ preds, bf16* __restrict__ xbuf) {
  __shared__ __align__(1024) char smem[2 * 8192];  // [A 4KB | W 4KB] x 2
  const int tid = threadIdx.x;
  const int lane = tid & 63;
  const int w = __builtin_amdgcn_readfirstlane(tid >> 6);
  const int bid = blockIdx.x;
  const int rest = bid >> 3;
  const int m0 = (rest >> nbits) * 64;
  const int n0 = (((bid & 7) << nbits) + (rest & ((1 << nbits) - 1))) * 64;
  const int lr = lane >> 2;
  const int slc = (((lane & 3) ^ ((lr >> 1) & 3)) << 3);
  const int cl = lane & 15, q = lane >> 4;
  const int sq16 = ((q ^ ((cl >> 1) & 3)) << 4);
  const int ns = K >> 5;

  f32x4 acc[4];
#pragma unroll
  for (int i = 0; i < 4; ++i) acc[i] = (f32x4){0.f, 0.f, 0.f, 0.f};

  auto stage = [&](int s, int b) {
    char* base = smem + b * 8192;
    const int k0 = (s << 5) + slc;
    if (w < 2) {
#pragma unroll
      for (int it = 0; it < 2; ++it) {
        const int r = (w * 2 + it) * 16;
        gld16(A + (long)(m0 + r + lr) * K + k0, base + r * 64);
      }
    } else {
#pragma unroll
      for (int it = 0; it < 2; ++it) {
        const int jj = (w - 2) * 2 + it;       // 0..3
        gld16(W + (long)(n0 + jj * 16 + lr) * K + k0, base + 4096 + jj * 1024);
      }
    }
  };

  stage(0, 0);
  int buf = 0;
  for (int s = 0; s < ns; ++s) {
    __syncthreads();
    if (s + 1 < ns) stage(s + 1, buf ^ 1);
    const char* base = smem + buf * 8192;
    const char* aB = base + cl * 64 + sq16;
    bf16x8 a0 = *(const bf16x8*)(aB);
    bf16x8 a1 = *(const bf16x8*)(aB + 1024);
    bf16x8 a2 = *(const bf16x8*)(aB + 2048);
    bf16x8 a3 = *(const bf16x8*)(aB + 3072);
    bf16x8 wf = *(const bf16x8*)(base + 4096 + (w * 16 + cl) * 64 + sq16);
    acc[0] = MFMA(a0, wf, acc[0]);
    acc[1] = MFMA(a1, wf, acc[1]);
    acc[2] = MFMA(a2, wf, acc[2]);
    acc[3] = MFMA(a3, wf, acc[3]);
    buf ^= 1;
  }

  const int j = n0 + w * 16 + cl;
  const float bj = bias[j];
#pragma unroll
  for (int mi = 0; mi < 4; ++mi)
#pragma unroll
    for (int r = 0; r < 4; ++r) {
      const int row = m0 + mi * 16 + q * 4 + r;
      float v = acc[mi][r] + bj;
      if (mode == 0) {
        v = fmaxf(v, 0.f);
        const int b = row >> 1, l = row & 1;   // x rows are (b, l) pairs
        if (l == 0) { o0f[(long)b * HD + j] = v; o0b[(long)b * HD + j] = __float2bfloat16(v); }
        else        { o1f[(long)b * HD + j] = v; o1b[(long)b * HD + j] = __float2bfloat16(v); }
      } else {
        preds[((long)row * TT + t) * OD + j] = v;
        xbuf[(long)row * OD + j] = __float2bfloat16(v);
      }
    }
}

// ---- naive fallbacks (only if workspace too small for bf16 weights) ----
__global__ __launch_bounds__(256) void gru_cell_naive(
    const bf16* __restrict__ Ax, int Kx, const bf16* __restrict__ Ahb,
    const float* __restrict__ hprevf,
    const float* __restrict__ Wih, const float* __restrict__ Whh,
    const float* __restrict__ bih, const float* __restrict__ bhh,
    float* __restrict__ houtf, bf16* __restrict__ houtb) {
  const int idx = blockIdx.x * 256 + threadIdx.x;
  if (idx >= BB * HD) return;
  const int b = idx / HD, j = idx % HD;
  float gr = bih[j] + bhh[j], gz = bih[j + HD] + bhh[j + HD];
  float gnx = bih[j + 2 * HD], gnh = bhh[j + 2 * HD];
  for (int k = 0; k < Kx; ++k) {
    const float xv = __bfloat162float(Ax[(long)b * Kx + k]);
    gr += xv * Wih[(long)j * Kx + k];
    gz += xv * Wih[((long)j + HD) * Kx + k];
    gnx += xv * Wih[((long)j + 2 * HD) * Kx + k];
  }
  for (int k = 0; k < HD; ++k) {
    const float hv = __bfloat162float(Ahb[(long)b * HD + k]);
    gr += hv * Whh[(long)j * HD + k];
    gz += hv * Whh[((long)j + HD) * HD + k];
    gnh += hv * Whh[((long)j + 2 * HD) * HD + k];
  }
  const float rr = 1.f / (1.f + __expf(-gr));
  const float zz = 1.f / (1.f + __expf(-gz));
  const float nn = tanhf(gnx + rr * gnh);
  const float hp = hprevf[(long)b * HD + j];
  const float hn = (1.f - zz) * nn + zz * hp;
  houtf[(long)b * HD + j] = hn;
  houtb[(long)b * HD + j] = __float2bfloat16(hn);
}

__global__ __launch_bounds__(256) void naive_gemm(
    const void* __restrict__ A, int abf, const float* __restrict__ W,
    const float* __restrict__ bias, int N, int K, int mode, int t,
    float* __restrict__ o0f, bf16* __restrict__ o0b,
    float* __restrict__ o1f, bf16* __restrict__ o1b,
    float* __restrict__ preds, bf16* __restrict__ xbuf) {
  const long idx = (long)blockIdx.x * 256 + threadIdx.x;
  const int row = idx / N, j = idx % N;
  float v = bias[j];
  for (int k = 0; k < K; ++k) {
    const float av = abf ? __bfloat162float(((const bf16*)A)[(long)row * K + k])
                         : ((const float*)A)[(long)row * K + k];
    v += av * W[(long)j * K + k];
  }
  if (mode == 0) {
    v = fmaxf(v, 0.f);
    const int b = row >> 1, l = row & 1;
    if (l == 0) { o0f[(long)b * HD + j] = v; o0b[(long)b * HD + j] = __float2bfloat16(v); }
    else        { o1f[(long)b * HD + j] = v; o1b[(long)b * HD + j] = __float2bfloat16(v); }
  } else {
    preds[((long)row * TT + t) * OD + j] = v;
    xbuf[(long)row * OD + j] = __float2bfloat16(v);
  }
}

extern "C" void kernel_launch(void* const* d_in, const int* in_sizes, int n_in,
                              void* d_out, int out_size, void* d_ws, size_t ws_size,
                              hipStream_t stream) {
  const float* x    = (const float*)d_in[0];
  const float* embW = (const float*)d_in[1];
  const float* embb = (const float*)d_in[2];
  const float* Wih0 = (const float*)d_in[3];
  const float* Whh0 = (const float*)d_in[4];
  const float* bih0 = (const float*)d_in[5];
  const float* bhh0 = (const float*)d_in[6];
  const float* Wih1 = (const float*)d_in[7];
  const float* Whh1 = (const float*)d_in[8];
  const float* bih1 = (const float*)d_in[9];
  const float* bhh1 = (const float*)d_in[10];
  const float* outW = (const float*)d_in[11];
  const float* outb = (const float*)d_in[12];
  float* preds = (float*)d_out;

  char* p = (char*)d_ws;
  const size_t HF = (size_t)BB * HD * 4;
  const size_t HB = (size_t)BB * HD * 2;
  float* h0f[2] = {(float*)p, (float*)(p + HF)}; p += 2 * HF;
  float* h1f[2] = {(float*)p, (float*)(p + HF)}; p += 2 * HF;
  bf16* h0b[2] = {(bf16*)p, (bf16*)(p + HB)}; p += 2 * HB;
  bf16* h1b[2] = {(bf16*)p, (bf16*)(p + HB)}; p += 2 * HB;
  bf16* xbuf = (bf16*)p; p += (size_t)BB * OD * 2;

  const int nE = 2048 * 1024, nI0 = 6144 * 512, nH = 6144 * 2048,
            nO = 512 * 2048, nX = 1024 * 1024;
  const size_t conv_bytes = 2ul * (nE + nI0 + 3ul * nH + nO + nX);
  const bool big = ws_size >= (size_t)(p - (char*)d_ws) + conv_bytes;

  hipMemsetAsync(xbuf, 0, (size_t)BB * OD * 2, stream);  // zero input, steps 0-1

  if (big) {
    bf16* embWc = (bf16*)p; p += 2ul * nE;
    bf16* Wih0c = (bf16*)p; p += 2ul * nI0;
    bf16* Whh0c = (bf16*)p; p += 2ul * nH;
    bf16* Wih1c = (bf16*)p; p += 2ul * nH;
    bf16* Whh1c = (bf16*)p; p += 2ul * nH;
    bf16* outWc = (bf16*)p; p += 2ul * nO;
    bf16* xbf   = (bf16*)p; p += 2ul * nX;
    auto cv = [&](const float* s, bf16* d, int n) {
      cvt_kernel<<<(n / 4 + 255) / 256, 256, 0, stream>>>(s, d, n / 4);
    };
    cv(embW, embWc, nE); cv(Wih0, Wih0c, nI0); cv(Whh0, Whh0c, nH);
    cv(Wih1, Wih1c, nH); cv(Whh1, Whh1c, nH); cv(outW, outWc, nO);
    cv(x, xbf, nX);

    // embedding: xbf [1024,1024] -> h0/h1; 16 m-tiles x 32 n-tiles
    gemm64_kernel<<<512, 256, 0, stream>>>(
        xbf, embWc, embb, 1024, 0, 0, 2,
        h0f[0], h0b[0], h1f[0], h1b[0], nullptr, nullptr);

    for (int s = 0; s < 33; ++s) {
      const int cur = s & 1, nxt = cur ^ 1;
      gru_cell_kernel<<<512, 256, 0, stream>>>(
          xbuf, OD, h0b[cur], h0f[cur], Wih0c, Whh0c, bih0, bhh0,
          h0f[nxt], h0b[nxt]);
      gru_cell_kernel<<<512, 256, 0, stream>>>(
          h0b[nxt], HD, h1b[cur], h1f[cur], Wih1c, Whh1c, bih1, bhh1,
          h1f[nxt], h1b[nxt]);
      if (s >= 1)
        gemm64_kernel<<<64, 256, 0, stream>>>(
            h1b[nxt], outWc, outb, HD, 1, s - 1, 0,
            nullptr, nullptr, nullptr, nullptr, preds, xbuf);
    }
  } else {
    naive_gemm<<<(1024 * 2048) / 256, 256, 0, stream>>>(
        x, 0, embW, embb, 2048, 1024, 0, 0,
        h0f[0], h0b[0], h1f[0], h1b[0], nullptr, nullptr);
    for (int s = 0; s < 33; ++s) {
      const int cur = s & 1, nxt = cur ^ 1;
      gru_cell_naive<<<(BB * HD + 255) / 256, 256, 0, stream>>>(
          xbuf, OD, h0b[cur], h0f[cur], Wih0, Whh0, bih0, bhh0,
          h0f[nxt], h0b[nxt]);
      gru_cell_naive<<<(BB * HD + 255) / 256, 256, 0, stream>>>(
          h0b[nxt], HD, h1b[cur], h1f[cur], Wih1, Whh1, bih1, bhh1,
          h1f[nxt], h1b[nxt]);
      if (s >= 1)
        naive_gemm<<<(512 * 512) / 256, 256, 0, stream>>>(
            h1b[nxt], 1, outW, outb, 512, 2048, 1, s - 1,
            nullptr, nullptr, nullptr, nullptr, preds, xbuf);
    }
  }
}

// Round 3
// 2788.238 us; speedup vs baseline: 1.7621x; 1.2948x over previous
//
#include <hip/hip_runtime.h>
#include <hip/hip_bf16.h>

using bf16 = __hip_bfloat16;
typedef __attribute__((ext_vector_type(8))) short bf16x8;
typedef __attribute__((ext_vector_type(4))) float f32x4;

static constexpr int HD = 2048;   // hidden
static constexpr int BB = 512;    // batch
static constexpr int OD = 512;    // output dim
static constexpr int TT = 32;     // time steps

#define MFMA(a, b, c) __builtin_amdgcn_mfma_f32_16x16x32_bf16((a), (b), (c), 0, 0, 0)

__device__ __forceinline__ void gld16(const void* g, void* l) {
  __builtin_amdgcn_global_load_lds((const __attribute__((address_space(1))) void*)g,
                                   (__attribute__((address_space(3))) void*)l, 16, 0, 0);
}

// one-time fp32 -> bf16 conversion
__global__ __launch_bounds__(256) void cvt_kernel(const float* __restrict__ s,
                                                  bf16* __restrict__ d, int n4) {
  const int i = blockIdx.x * 256 + threadIdx.x;
  if (i < n4) {
    const float4 v = ((const float4*)s)[i];
    union { unsigned long long u; bf16 e[4]; } o;
    o.e[0] = __float2bfloat16(v.x); o.e[1] = __float2bfloat16(v.y);
    o.e[2] = __float2bfloat16(v.z); o.e[3] = __float2bfloat16(v.w);
    *(unsigned long long*)(d + 4l * i) = o.u;
  }
}

// Fused GRU cell. Round-2 structure (single-barrier dbuf, swizzle, grid 512 =
// 2 blocks/CU) with BK 32 -> 64: half the barriers/vmcnt-drains, 2x compute
// per step (12 MFMA + 10 ds_read_b128 per wave per step).
// Block: 64m x 32n x 3 gates, 4 waves; wave = 32m x 16n x 3 gates.
// LDS dbuf 2 x 20KB ([A 8KB | W 12KB]); rows are 128B (64 x bf16).
// Swizzle: LDS 16B-col c of row r holds global k-chunk c ^ (r&7); gld16 dest
// stays linear (rule 21): stage pre-swizzles the *global* column
// (gcol = (lane&7)^(lane>>3), since LDS col = lane&7, row = lane>>3);
// reads use col' = ((h<<2)|q) ^ (cl&7).
#define CELL_STEP(NACC, STAGE_CALL)                                            \
  {                                                                            \
    __syncthreads();                                                           \
    STAGE_CALL;                                                                \
    const char* base = smem + buf * 20480;                                     \
    const char* aB = base + (wm * 32 + cl) * 128;                              \
    const char* wB = base + 8192 + (wn * 16 + cl) * 128;                       \
    bf16x8 a00 = *(const bf16x8*)(aB + sc0);                                   \
    bf16x8 a01 = *(const bf16x8*)(aB + sc1);                                   \
    bf16x8 a10 = *(const bf16x8*)(aB + 2048 + sc0);                            \
    bf16x8 a11 = *(const bf16x8*)(aB + 2048 + sc1);                            \
    bf16x8 w00 = *(const bf16x8*)(wB + sc0);                                   \
    bf16x8 w01 = *(const bf16x8*)(wB + sc1);                                   \
    bf16x8 w10 = *(const bf16x8*)(wB + 4096 + sc0);                            \
    bf16x8 w11 = *(const bf16x8*)(wB + 4096 + sc1);                            \
    bf16x8 w20 = *(const bf16x8*)(wB + 8192 + sc0);                            \
    bf16x8 w21 = *(const bf16x8*)(wB + 8192 + sc1);                            \
    acc[0][0] = MFMA(a00, w00, acc[0][0]);                                     \
    acc[0][1] = MFMA(a10, w00, acc[0][1]);                                     \
    acc[1][0] = MFMA(a00, w10, acc[1][0]);                                     \
    acc[1][1] = MFMA(a10, w10, acc[1][1]);                                     \
    acc[NACC][0] = MFMA(a00, w20, acc[NACC][0]);                               \
    acc[NACC][1] = MFMA(a10, w20, acc[NACC][1]);                               \
    acc[0][0] = MFMA(a01, w01, acc[0][0]);                                     \
    acc[0][1] = MFMA(a11, w01, acc[0][1]);                                     \
    acc[1][0] = MFMA(a01, w11, acc[1][0]);                                     \
    acc[1][1] = MFMA(a11, w11, acc[1][1]);                                     \
    acc[NACC][0] = MFMA(a01, w21, acc[NACC][0]);                               \
    acc[NACC][1] = MFMA(a11, w21, acc[NACC][1]);                               \
    buf ^= 1;                                                                  \
  }

__global__ __launch_bounds__(256) void gru_cell_kernel(
    const bf16* __restrict__ Ax, int Kx,        // [B, Kx] bf16 layer input
    const bf16* __restrict__ Ahb,               // [B, H] bf16 h shadow
    const float* __restrict__ hprevf,           // [B, H] fp32 h master
    const bf16* __restrict__ Wih,               // [3H, Kx] bf16
    const bf16* __restrict__ Whh,               // [3H, H] bf16
    const float* __restrict__ bih, const float* __restrict__ bhh,
    float* __restrict__ houtf, bf16* __restrict__ houtb) {
  __shared__ __align__(1024) char smem[2 * 20480];  // [A 8KB | W 12KB] x 2
  const int tid = threadIdx.x;
  const int lane = tid & 63;
  const int w = __builtin_amdgcn_readfirstlane(tid >> 6);
  const int wm = w >> 1, wn = w & 1;
  const int bid = blockIdx.x;
  const int rest = bid >> 3;
  const int m0 = (rest >> 3) * 64;                // 8 m-groups
  const int n0 = ((bid & 7) * 8 + (rest & 7)) * 32;  // same-n -> same XCD
  const int lr8 = lane >> 3;                       // stage: row within 8
  const int gsw = ((lane & 7) ^ lr8) << 3;         // stage: swizzled k-elem off
  const int cl = lane & 15, q = lane >> 4;
  const int sc0 = ((q ^ (cl & 7)) << 4);           // read: swizzled col, h=0
  const int sc1 = sc0 ^ 64;                        // h=1
  const int nsa = Kx >> 6, nsb = HD >> 6;

  // acc: 0=r, 1=z (both phases), 2=gx_n (A), 3=gh_n (B); [gate][m-frag]
  f32x4 acc[4][2];
#pragma unroll
  for (int a = 0; a < 4; ++a)
#pragma unroll
    for (int i = 0; i < 2; ++i) acc[a][i] = (f32x4){0.f, 0.f, 0.f, 0.f};

  // stage K-slice s (64 wide) of (Ap,Wp) into buffer b. Each gld16 issue:
  // 8 rows x 128B = 1KB. waves 0-1: A (4 issues); waves 2-3: W (6 issues).
  auto stage = [&](const bf16* Ap, const bf16* Wp, int K, int s, int b) {
    char* base = smem + b * 20480;
    const int k0 = (s << 6) + gsw;
    if (w < 2) {
#pragma unroll
      for (int it = 0; it < 4; ++it) {
        const int r0 = (w * 4 + it) * 8;
        gld16(Ap + (long)(m0 + r0 + lr8) * K + k0, base + r0 * 128);
      }
    } else {
#pragma unroll
      for (int it = 0; it < 6; ++it) {
        const int jj = (w - 2) * 6 + it;           // 0..11: gate jj>>2, nn (jj&3)*8
        gld16(Wp + ((long)(jj >> 2) * HD + n0 + (jj & 3) * 8 + lr8) * K + k0,
              base + 8192 + jj * 1024);
      }
    }
  };

  stage(Ax, Wih, Kx, 0, 0);
  int buf = 0;
  for (int s = 0; s < nsa; ++s)                  // phase A: x @ Wih^T
    CELL_STEP(2, if (s + 1 < nsa) stage(Ax, Wih, Kx, s + 1, buf ^ 1);
                 else stage(Ahb, Whh, HD, 0, buf ^ 1));
  for (int s = 0; s < nsb; ++s)                  // phase B: h @ Whh^T
    CELL_STEP(3, if (s + 1 < nsb) stage(Ahb, Whh, HD, s + 1, buf ^ 1));

  // C/D layout: col=lane&15, row=(lane>>4)*4+reg (m89-verified)
  const int j = n0 + wn * 16 + cl;
  const float bihr = bih[j], bihz = bih[j + HD], bihn = bih[j + 2 * HD];
  const float bhhr = bhh[j], bhhz = bhh[j + HD], bhhn = bhh[j + 2 * HD];
#pragma unroll
  for (int mi = 0; mi < 2; ++mi)
#pragma unroll
    for (int r = 0; r < 4; ++r) {
      const int b = m0 + wm * 32 + mi * 16 + q * 4 + r;
      const float gr = acc[0][mi][r] + bihr + bhhr;
      const float gz = acc[1][mi][r] + bihz + bhhz;
      const float gnx = acc[2][mi][r] + bihn;
      const float gnh = acc[3][mi][r] + bhhn;
      const float rr = 1.f / (1.f + __expf(-gr));
      const float zz = 1.f / (1.f + __expf(-gz));
      const float nn = tanhf(gnx + rr * gnh);
      const float hp = hprevf[(long)b * HD + j];
      const float hn = (1.f - zz) * nn + zz * hp;
      houtf[(long)b * HD + j] = hn;
      houtb[(long)b * HD + j] = __float2bfloat16(hn);
    }
}

// C = A @ W^T + bias, tile 64m x 64n, 4 waves (wave = 64m x 16n), BK=64,
// single-barrier dbuf + LDS swizzle (128B rows). A,W bf16.
// mode 0: embedding — relu, scatter rows (b*2+l) into h0/h1 (fp32+bf16)
// mode 1: projection — preds[b,t,:] fp32 + xbuf bf16
__global__ __launch_bounds__(256) void gemm64_kernel(
    const bf16* __restrict__ A, const bf16* __restrict__ W,
    const float* __restrict__ bias, int K, int mode, int t, int nbits,
    float* __restrict__ o0f, bf16* __restrict__ o0b,
    float* __restrict__ o1f, bf16* __restrict__ o1b,
    float* __restrict__ preds, bf16* __restrict__ xbuf) {
  __shared__ __align__(1024) char smem[2 * 16384];  // [A 8KB | W 8KB] x 2
  const int tid = threadIdx.x;
  const int lane = tid & 63;
  const int w = __builtin_amdgcn_readfirstlane(tid >> 6);
  const int bid = blockIdx.x;
  const int rest = bid >> 3;
  const int m0 = (rest >> nbits) * 64;
  const int n0 = (((bid & 7) << nbits) + (rest & ((1 << nbits) - 1))) * 64;
  const int lr8 = lane >> 3;
  const int gsw = ((lane & 7) ^ lr8) << 3;
  const int cl = lane & 15, q = lane >> 4;
  const int sc0 = ((q ^ (cl & 7)) << 4);
  const int sc1 = sc0 ^ 64;
  const int ns = K >> 6;

  f32x4 acc[4];
#pragma unroll
  for (int i = 0; i < 4; ++i) acc[i] = (f32x4){0.f, 0.f, 0.f, 0.f};

  auto stage = [&](int s, int b) {
    char* base = smem + b * 16384;
    const int k0 = (s << 6) + gsw;
    if (w < 2) {
#pragma unroll
      for (int it = 0; it < 4; ++it) {
        const int r0 = (w * 4 + it) * 8;
        gld16(A + (long)(m0 + r0 + lr8) * K + k0, base + r0 * 128);
      }
    } else {
#pragma unroll
      for (int it = 0; it < 4; ++it) {
        const int jj = (w - 2) * 4 + it;           // 0..7
        gld16(W + (long)(n0 + jj * 8 + lr8) * K + k0, base + 8192 + jj * 1024);
      }
    }
  };

  stage(0, 0);
  int buf = 0;
  for (int s = 0; s < ns; ++s) {
    __syncthreads();
    if (s + 1 < ns) stage(s + 1, buf ^ 1);
    const char* base = smem + buf * 16384;
    const char* aB = base + cl * 128;
    const char* wB = base + 8192 + (w * 16 + cl) * 128;
    bf16x8 a00 = *(const bf16x8*)(aB + sc0);
    bf16x8 a01 = *(const bf16x8*)(aB + sc1);
    bf16x8 a10 = *(const bf16x8*)(aB + 2048 + sc0);
    bf16x8 a11 = *(const bf16x8*)(aB + 2048 + sc1);
    bf16x8 a20 = *(const bf16x8*)(aB + 4096 + sc0);
    bf16x8 a21 = *(const bf16x8*)(aB + 4096 + sc1);
    bf16x8 a30 = *(const bf16x8*)(aB + 6144 + sc0);
    bf16x8 a31 = *(const bf16x8*)(aB + 6144 + sc1);
    bf16x8 w0 = *(const bf16x8*)(wB + sc0);
    bf16x8 w1 = *(const bf16x8*)(wB + sc1);
    acc[0] = MFMA(a00, w0, acc[0]);
    acc[1] = MFMA(a10, w0, acc[1]);
    acc[2] = MFMA(a20, w0, acc[2]);
    acc[3] = MFMA(a30, w0, acc[3]);
    acc[0] = MFMA(a01, w1, acc[0]);
    acc[1] = MFMA(a11, w1, acc[1]);
    acc[2] = MFMA(a21, w1, acc[2]);
    acc[3] = MFMA(a31, w1, acc[3]);
    buf ^= 1;
  }

  const int j = n0 + w * 16 + cl;
  const float bj = bias[j];
#pragma unroll
  for (int mi = 0; mi < 4; ++mi)
#pragma unroll
    for (int r = 0; r < 4; ++r) {
      const int row = m0 + mi * 16 + q * 4 + r;
      float v = acc[mi][r] + bj;
      if (mode == 0) {
        v = fmaxf(v, 0.f);
        const int b = row >> 1, l = row & 1;   // x rows are (b, l) pairs
        if (l == 0) { o0f[(long)b * HD + j] = v; o0b[(long)b * HD + j] = __float2bfloat16(v); }
        else        { o1f[(long)b * HD + j] = v; o1b[(long)b * HD + j] = __float2bfloat16(v); }
      } else {
        preds[((long)row * TT + t) * OD + j] = v;
        xbuf[(long)row * OD + j] = __float2bfloat16(v);
      }
    }
}

// ---- naive fallbacks (only if workspace too small for bf16 weights) ----
__global__ __launch_bounds__(256) void gru_cell_naive(
    const bf16* __restrict__ Ax, int Kx, const bf16* __restrict__ Ahb,
    const float* __restrict__ hprevf,
    const float* __restrict__ Wih, const float* __restrict__ Whh,
    const float* __restrict__ bih, const float* __restrict__ bhh,
    float* __restrict__ houtf, bf16* __restrict__ houtb) {
  const int idx = blockIdx.x * 256 + threadIdx.x;
  if (idx >= BB * HD) return;
  const int b = idx / HD, j = idx % HD;
  float gr = bih[j] + bhh[j], gz = bih[j + HD] + bhh[j + HD];
  float gnx = bih[j + 2 * HD], gnh = bhh[j + 2 * HD];
  for (int k = 0; k < Kx; ++k) {
    const float xv = __bfloat162float(Ax[(long)b * Kx + k]);
    gr += xv * Wih[(long)j * Kx + k];
    gz += xv * Wih[((long)j + HD) * Kx + k];
    gnx += xv * Wih[((long)j + 2 * HD) * Kx + k];
  }
  for (int k = 0; k < HD; ++k) {
    const float hv = __bfloat162float(Ahb[(long)b * HD + k]);
    gr += hv * Whh[(long)j * HD + k];
    gz += hv * Whh[((long)j + HD) * HD + k];
    gnh += hv * Whh[((long)j + 2 * HD) * HD + k];
  }
  const float rr = 1.f / (1.f + __expf(-gr));
  const float zz = 1.f / (1.f + __expf(-gz));
  const float nn = tanhf(gnx + rr * gnh);
  const float hp = hprevf[(long)b * HD + j];
  const float hn = (1.f - zz) * nn + zz * hp;
  houtf[(long)b * HD + j] = hn;
  houtb[(long)b * HD + j] = __float2bfloat16(hn);
}

__global__ __launch_bounds__(256) void naive_gemm(
    const void* __restrict__ A, int abf, const float* __restrict__ W,
    const float* __restrict__ bias, int N, int K, int mode, int t,
    float* __restrict__ o0f, bf16* __restrict__ o0b,
    float* __restrict__ o1f, bf16* __restrict__ o1b,
    float* __restrict__ preds, bf16* __restrict__ xbuf) {
  const long idx = (long)blockIdx.x * 256 + threadIdx.x;
  const int row = idx / N, j = idx % N;
  float v = bias[j];
  for (int k = 0; k < K; ++k) {
    const float av = abf ? __bfloat162float(((const bf16*)A)[(long)row * K + k])
                         : ((const float*)A)[(long)row * K + k];
    v += av * W[(long)j * K + k];
  }
  if (mode == 0) {
    v = fmaxf(v, 0.f);
    const int b = row >> 1, l = row & 1;
    if (l == 0) { o0f[(long)b * HD + j] = v; o0b[(long)b * HD + j] = __float2bfloat16(v); }
    else        { o1f[(long)b * HD + j] = v; o1b[(long)b * HD + j] = __float2bfloat16(v); }
  } else {
    preds[((long)row * TT + t) * OD + j] = v;
    xbuf[(long)row * OD + j] = __float2bfloat16(v);
  }
}

extern "C" void kernel_launch(void* const* d_in, const int* in_sizes, int n_in,
                              void* d_out, int out_size, void* d_ws, size_t ws_size,
                              hipStream_t stream) {
  const float* x    = (const float*)d_in[0];
  const float* embW = (const float*)d_in[1];
  const float* embb = (const float*)d_in[2];
  const float* Wih0 = (const float*)d_in[3];
  const float* Whh0 = (const float*)d_in[4];
  const float* bih0 = (const float*)d_in[5];
  const float* bhh0 = (const float*)d_in[6];
  const float* Wih1 = (const float*)d_in[7];
  const float* Whh1 = (const float*)d_in[8];
  const float* bih1 = (const float*)d_in[9];
  const float* bhh1 = (const float*)d_in[10];
  const float* outW = (const float*)d_in[11];
  const float* outb = (const float*)d_in[12];
  float* preds = (float*)d_out;

  char* p = (char*)d_ws;
  const size_t HF = (size_t)BB * HD * 4;
  const size_t HB = (size_t)BB * HD * 2;
  float* h0f[2] = {(float*)p, (float*)(p + HF)}; p += 2 * HF;
  float* h1f[2] = {(float*)p, (float*)(p + HF)}; p += 2 * HF;
  bf16* h0b[2] = {(bf16*)p, (bf16*)(p + HB)}; p += 2 * HB;
  bf16* h1b[2] = {(bf16*)p, (bf16*)(p + HB)}; p += 2 * HB;
  bf16* xbuf = (bf16*)p; p += (size_t)BB * OD * 2;

  const int nE = 2048 * 1024, nI0 = 6144 * 512, nH = 6144 * 2048,
            nO = 512 * 2048, nX = 1024 * 1024;
  const size_t conv_bytes = 2ul * (nE + nI0 + 3ul * nH + nO + nX);
  const bool big = ws_size >= (size_t)(p - (char*)d_ws) + conv_bytes;

  hipMemsetAsync(xbuf, 0, (size_t)BB * OD * 2, stream);  // zero input, steps 0-1

  if (big) {
    bf16* embWc = (bf16*)p; p += 2ul * nE;
    bf16* Wih0c = (bf16*)p; p += 2ul * nI0;
    bf16* Whh0c = (bf16*)p; p += 2ul * nH;
    bf16* Wih1c = (bf16*)p; p += 2ul * nH;
    bf16* Whh1c = (bf16*)p; p += 2ul * nH;
    bf16* outWc = (bf16*)p; p += 2ul * nO;
    bf16* xbf   = (bf16*)p; p += 2ul * nX;
    auto cv = [&](const float* s, bf16* d, int n) {
      cvt_kernel<<<(n / 4 + 255) / 256, 256, 0, stream>>>(s, d, n / 4);
    };
    cv(embW, embWc, nE); cv(Wih0, Wih0c, nI0); cv(Whh0, Whh0c, nH);
    cv(Wih1, Wih1c, nH); cv(Whh1, Whh1c, nH); cv(outW, outWc, nO);
    cv(x, xbf, nX);

    // embedding: xbf [1024,1024] -> h0/h1; 16 m-tiles x 32 n-tiles
    gemm64_kernel<<<512, 256, 0, stream>>>(
        xbf, embWc, embb, 1024, 0, 0, 2,
        h0f[0], h0b[0], h1f[0], h1b[0], nullptr, nullptr);

    for (int s = 0; s < 33; ++s) {
      const int cur = s & 1, nxt = cur ^ 1;
      gru_cell_kernel<<<512, 256, 0, stream>>>(
          xbuf, OD, h0b[cur], h0f[cur], Wih0c, Whh0c, bih0, bhh0,
          h0f[nxt], h0b[nxt]);
      gru_cell_kernel<<<512, 256, 0, stream>>>(
          h0b[nxt], HD, h1b[cur], h1f[cur], Wih1c, Whh1c, bih1, bhh1,
          h1f[nxt], h1b[nxt]);
      if (s >= 1)
        gemm64_kernel<<<64, 256, 0, stream>>>(
            h1b[nxt], outWc, outb, HD, 1, s - 1, 0,
            nullptr, nullptr, nullptr, nullptr, preds, xbuf);
    }
  } else {
    naive_gemm<<<(1024 * 2048) / 256, 256, 0, stream>>>(
        x, 0, embW, embb, 2048, 1024, 0, 0,
        h0f[0], h0b[0], h1f[0], h1b[0], nullptr, nullptr);
    for (int s = 0; s < 33; ++s) {
      const int cur = s & 1, nxt = cur ^ 1;
      gru_cell_naive<<<(BB * HD + 255) / 256, 256, 0, stream>>>(
          xbuf, OD, h0b[cur], h0f[cur], Wih0, Whh0, bih0, bhh0,
          h0f[nxt], h0b[nxt]);
      gru_cell_naive<<<(BB * HD + 255) / 256, 256, 0, stream>>>(
          h0b[nxt], HD, h1b[cur], h1f[cur], Wih1, Whh1, bih1, bhh1,
          h1f[nxt], h1b[nxt]);
      if (s >= 1)
        naive_gemm<<<(512 * 512) / 256, 256, 0, stream>>>(
            h1b[nxt], 1, outW, outb, 512, 2048, 1, s - 1,
            nullptr, nullptr, nullptr, nullptr, preds, xbuf);
    }
  }
}

// Round 4
// 2553.960 us; speedup vs baseline: 1.9238x; 1.0917x over previous
//
#include <hip/hip_runtime.h>
#include <hip/hip_bf16.h>

using bf16 = __hip_bfloat16;
typedef __attribute__((ext_vector_type(8))) short bf16x8;
typedef __attribute__((ext_vector_type(4))) float f32x4;

static constexpr int HD = 2048;   // hidden
static constexpr int BB = 512;    // batch
static constexpr int OD = 512;    // output dim
static constexpr int TT = 32;     // time steps

#define MFMA(a, b, c) __builtin_amdgcn_mfma_f32_16x16x32_bf16((a), (b), (c), 0, 0, 0)

__device__ __forceinline__ void gld16(const void* g, void* l) {
  __builtin_amdgcn_global_load_lds((const __attribute__((address_space(1))) void*)g,
                                   (__attribute__((address_space(3))) void*)l, 16, 0, 0);
}

// one-time fp32 -> bf16 conversion
__global__ __launch_bounds__(256) void cvt_kernel(const float* __restrict__ s,
                                                  bf16* __restrict__ d, int n4) {
  const int i = blockIdx.x * 256 + threadIdx.x;
  if (i < n4) {
    const float4 v = ((const float4*)s)[i];
    union { unsigned long long u; bf16 e[4]; } o;
    o.e[0] = __float2bfloat16(v.x); o.e[1] = __float2bfloat16(v.y);
    o.e[2] = __float2bfloat16(v.z); o.e[3] = __float2bfloat16(v.w);
    *(unsigned long long*)(d + 4l * i) = o.u;
  }
}

// Fused GRU cell. Round-3 structure (BK=64, swizzle, grid 512 = 2 blocks/CU)
// with the vmcnt(0) barrier drain replaced by a 3-buffer depth-2 counted-vmcnt
// pipeline (T4): per step {s_waitcnt vmcnt(own); s_barrier} where own = this
// wave's gld16 issues per slice (A-waves 4, W-waves 6); stage(s+2) issued
// after the barrier. Slice s is waited on 2 full steps after issue (~3200cyc
// >> 900cyc HBM latency) -> exposed drain ~0; stage(s+1) stays in flight
// across the barrier. Last step uses vmcnt(0) (counted wait is vacuous once
// staging stops). 3-buffer overwrite is barrier-ordered.
// Block: 64m x 32n x 3 gates, 4 waves; wave = 32m x 16n x 3 gates
// (12 MFMA + 10 ds_read_b128 per BK=64 step). LDS 3 x 20KB ([A 8KB | W 12KB]).
// Swizzle: LDS 16B-col c of row r holds global k-chunk c ^ (r&7) (round-1/3
// verified, conflicts = 0).
#define CELL_COMPUTE(NACC)                                                     \
  {                                                                            \
    const char* aB = rb + (wm * 32 + cl) * 128;                                \
    const char* wB = rb + 8192 + (wn * 16 + cl) * 128;                         \
    bf16x8 a00 = *(const bf16x8*)(aB + sc0);                                   \
    bf16x8 a01 = *(const bf16x8*)(aB + sc1);                                   \
    bf16x8 a10 = *(const bf16x8*)(aB + 2048 + sc0);                            \
    bf16x8 a11 = *(const bf16x8*)(aB + 2048 + sc1);                            \
    bf16x8 w00 = *(const bf16x8*)(wB + sc0);                                   \
    bf16x8 w01 = *(const bf16x8*)(wB + sc1);                                   \
    bf16x8 w10 = *(const bf16x8*)(wB + 4096 + sc0);                            \
    bf16x8 w11 = *(const bf16x8*)(wB + 4096 + sc1);                            \
    bf16x8 w20 = *(const bf16x8*)(wB + 8192 + sc0);                            \
    bf16x8 w21 = *(const bf16x8*)(wB + 8192 + sc1);                            \
    acc[0][0] = MFMA(a00, w00, acc[0][0]);                                     \
    acc[0][1] = MFMA(a10, w00, acc[0][1]);                                     \
    acc[1][0] = MFMA(a00, w10, acc[1][0]);                                     \
    acc[1][1] = MFMA(a10, w10, acc[1][1]);                                     \
    acc[NACC][0] = MFMA(a00, w20, acc[NACC][0]);                               \
    acc[NACC][1] = MFMA(a10, w20, acc[NACC][1]);                               \
    acc[0][0] = MFMA(a01, w01, acc[0][0]);                                     \
    acc[0][1] = MFMA(a11, w01, acc[0][1]);                                     \
    acc[1][0] = MFMA(a01, w11, acc[1][0]);                                     \
    acc[1][1] = MFMA(a11, w11, acc[1][1]);                                     \
    acc[NACC][0] = MFMA(a01, w21, acc[NACC][0]);                               \
    acc[NACC][1] = MFMA(a11, w21, acc[NACC][1]);                               \
  }

#define CELL_ROT(P) P = (P == smem + 2 * 20480) ? smem : P + 20480;

#define CELL_STEP(NACC, STAGE_CALL)                                            \
  {                                                                            \
    if (w < 2) asm volatile("s_waitcnt vmcnt(4)\n\ts_barrier" ::: "memory");   \
    else       asm volatile("s_waitcnt vmcnt(6)\n\ts_barrier" ::: "memory");   \
    STAGE_CALL;                                                                \
    CELL_COMPUTE(NACC);                                                        \
    CELL_ROT(rb); CELL_ROT(sb);                                                \
  }

#define CELL_STEP_LAST(NACC)                                                   \
  {                                                                            \
    asm volatile("s_waitcnt vmcnt(0)\n\ts_barrier" ::: "memory");              \
    CELL_COMPUTE(NACC);                                                        \
  }

__global__ __launch_bounds__(256) void gru_cell_kernel(
    const bf16* __restrict__ Ax, int Kx,        // [B, Kx] bf16 layer input
    const bf16* __restrict__ Ahb,               // [B, H] bf16 h shadow
    const float* __restrict__ hprevf,           // [B, H] fp32 h master
    const bf16* __restrict__ Wih,               // [3H, Kx] bf16
    const bf16* __restrict__ Whh,               // [3H, H] bf16
    const float* __restrict__ bih, const float* __restrict__ bhh,
    float* __restrict__ houtf, bf16* __restrict__ houtb) {
  __shared__ __align__(1024) char smem[3 * 20480];  // [A 8KB | W 12KB] x 3
  const int tid = threadIdx.x;
  const int lane = tid & 63;
  const int w = __builtin_amdgcn_readfirstlane(tid >> 6);
  const int wm = w >> 1, wn = w & 1;
  const int bid = blockIdx.x;
  const int rest = bid >> 3;
  const int m0 = (rest >> 3) * 64;                // 8 m-groups
  const int n0 = ((bid & 7) * 8 + (rest & 7)) * 32;  // same-n -> same XCD
  const int lr8 = lane >> 3;                       // stage: row within 8
  const int gsw = ((lane & 7) ^ lr8) << 3;         // stage: swizzled k-elem off
  const int cl = lane & 15, q = lane >> 4;
  const int sc0 = ((q ^ (cl & 7)) << 4);           // read: swizzled col, h=0
  const int sc1 = sc0 ^ 64;                        // h=1
  const int nsa = Kx >> 6, nsb = HD >> 6;

  // acc: 0=r, 1=z (both phases), 2=gx_n (A), 3=gh_n (B); [gate][m-frag]
  f32x4 acc[4][2];
#pragma unroll
  for (int a = 0; a < 4; ++a)
#pragma unroll
    for (int i = 0; i < 2; ++i) acc[a][i] = (f32x4){0.f, 0.f, 0.f, 0.f};

  // stage K-slice s (64 wide) of (Ap,Wp) into buffer at base. Each gld16:
  // 8 rows x 128B = 1KB. waves 0-1: A (4 issues); waves 2-3: W (6 issues).
  auto stage = [&](const bf16* Ap, const bf16* Wp, int K, int s, char* base) {
    const int k0 = (s << 6) + gsw;
    if (w < 2) {
#pragma unroll
      for (int it = 0; it < 4; ++it) {
        const int r0 = (w * 4 + it) * 8;
        gld16(Ap + (long)(m0 + r0 + lr8) * K + k0, base + r0 * 128);
      }
    } else {
#pragma unroll
      for (int it = 0; it < 6; ++it) {
        const int jj = (w - 2) * 6 + it;           // 0..11: gate jj>>2, nn (jj&3)*8
        gld16(Wp + ((long)(jj >> 2) * HD + n0 + (jj & 3) * 8 + lr8) * K + k0,
              base + 8192 + jj * 1024);
      }
    }
  };

  stage(Ax, Wih, Kx, 0, smem);
  stage(Ax, Wih, Kx, 1, smem + 20480);   // nsa >= 8 always, slice 1 is phase A
  char* rb = smem;
  char* sb = smem + 2 * 20480;

  for (int s = 0; s < nsa; ++s)                  // phase A: x @ Wih^T
    CELL_STEP(2, if (s + 2 < nsa) stage(Ax, Wih, Kx, s + 2, sb);
                 else stage(Ahb, Whh, HD, s + 2 - nsa, sb));
  for (int s = 0; s < nsb - 1; ++s)              // phase B: h @ Whh^T
    CELL_STEP(3, if (s + 2 < nsb) stage(Ahb, Whh, HD, s + 2, sb));
  CELL_STEP_LAST(3);

  // C/D layout: col=lane&15, row=(lane>>4)*4+reg (m89-verified)
  const int j = n0 + wn * 16 + cl;
  const float bihr = bih[j], bihz = bih[j + HD], bihn = bih[j + 2 * HD];
  const float bhhr = bhh[j], bhhz = bhh[j + HD], bhhn = bhh[j + 2 * HD];
#pragma unroll
  for (int mi = 0; mi < 2; ++mi)
#pragma unroll
    for (int r = 0; r < 4; ++r) {
      const int b = m0 + wm * 32 + mi * 16 + q * 4 + r;
      const float gr = acc[0][mi][r] + bihr + bhhr;
      const float gz = acc[1][mi][r] + bihz + bhhz;
      const float gnx = acc[2][mi][r] + bihn;
      const float gnh = acc[3][mi][r] + bhhn;
      const float rr = 1.f / (1.f + __expf(-gr));
      const float zz = 1.f / (1.f + __expf(-gz));
      const float nn = tanhf(gnx + rr * gnh);
      const float hp = hprevf[(long)b * HD + j];
      const float hn = (1.f - zz) * nn + zz * hp;
      houtf[(long)b * HD + j] = hn;
      houtb[(long)b * HD + j] = __float2bfloat16(hn);
    }
}

// C = A @ W^T + bias, tile 64m x 64n, 4 waves (wave = 64m x 16n), BK=64,
// 3-buffer depth-2 counted-vmcnt (4 issues/wave/slice -> vmcnt(4)) + swizzle.
// mode 0: embedding — relu, scatter rows (b*2+l) into h0/h1 (fp32+bf16)
// mode 1: projection — preds[b,t,:] fp32 + xbuf bf16
#define G64_COMPUTE                                                            \
  {                                                                            \
    const char* aB = rb + cl * 128;                                            \
    const char* wB = rb + 8192 + (w * 16 + cl) * 128;                          \
    bf16x8 a00 = *(const bf16x8*)(aB + sc0);                                   \
    bf16x8 a01 = *(const bf16x8*)(aB + sc1);                                   \
    bf16x8 a10 = *(const bf16x8*)(aB + 2048 + sc0);                            \
    bf16x8 a11 = *(const bf16x8*)(aB + 2048 + sc1);                            \
    bf16x8 a20 = *(const bf16x8*)(aB + 4096 + sc0);                            \
    bf16x8 a21 = *(const bf16x8*)(aB + 4096 + sc1);                            \
    bf16x8 a30 = *(const bf16x8*)(aB + 6144 + sc0);                            \
    bf16x8 a31 = *(const bf16x8*)(aB + 6144 + sc1);                            \
    bf16x8 w0 = *(const bf16x8*)(wB + sc0);                                    \
    bf16x8 w1 = *(const bf16x8*)(wB + sc1);                                    \
    acc[0] = MFMA(a00, w0, acc[0]);                                            \
    acc[1] = MFMA(a10, w0, acc[1]);                                            \
    acc[2] = MFMA(a20, w0, acc[2]);                                            \
    acc[3] = MFMA(a30, w0, acc[3]);                                            \
    acc[0] = MFMA(a01, w1, acc[0]);                                            \
    acc[1] = MFMA(a11, w1, acc[1]);                                            \
    acc[2] = MFMA(a21, w1, acc[2]);                                            \
    acc[3] = MFMA(a31, w1, acc[3]);                                            \
  }

__global__ __launch_bounds__(256) void gemm64_kernel(
    const bf16* __restrict__ A, const bf16* __restrict__ W,
    const float* __restrict__ bias, int K, int mode, int t, int nbits,
    float* __restrict__ o0f, bf16* __restrict__ o0b,
    float* __restrict__ o1f, bf16* __restrict__ o1b,
    float* __restrict__ preds, bf16* __restrict__ xbuf) {
  __shared__ __align__(1024) char smem[3 * 16384];  // [A 8KB | W 8KB] x 3
  const int tid = threadIdx.x;
  const int lane = tid & 63;
  const int w = __builtin_amdgcn_readfirstlane(tid >> 6);
  const int bid = blockIdx.x;
  const int rest = bid >> 3;
  const int m0 = (rest >> nbits) * 64;
  const int n0 = (((bid & 7) << nbits) + (rest & ((1 << nbits) - 1))) * 64;
  const int lr8 = lane >> 3;
  const int gsw = ((lane & 7) ^ lr8) << 3;
  const int cl = lane & 15, q = lane >> 4;
  const int sc0 = ((q ^ (cl & 7)) << 4);
  const int sc1 = sc0 ^ 64;
  const int ns = K >> 6;

  f32x4 acc[4];
#pragma unroll
  for (int i = 0; i < 4; ++i) acc[i] = (f32x4){0.f, 0.f, 0.f, 0.f};

  auto stage = [&](int s, char* base) {
    const int k0 = (s << 6) + gsw;
    if (w < 2) {
#pragma unroll
      for (int it = 0; it < 4; ++it) {
        const int r0 = (w * 4 + it) * 8;
        gld16(A + (long)(m0 + r0 + lr8) * K + k0, base + r0 * 128);
      }
    } else {
#pragma unroll
      for (int it = 0; it < 4; ++it) {
        const int jj = (w - 2) * 4 + it;           // 0..7
        gld16(W + (long)(n0 + jj * 8 + lr8) * K + k0, base + 8192 + jj * 1024);
      }
    }
  };

  stage(0, smem);
  stage(1, smem + 16384);
  char* rb = smem;
  char* sb = smem + 2 * 16384;

  for (int s = 0; s < ns - 1; ++s) {
    asm volatile("s_waitcnt vmcnt(4)\n\ts_barrier" ::: "memory");
    if (s + 2 < ns) stage(s + 2, sb);
    G64_COMPUTE;
    rb = (rb == smem + 2 * 16384) ? smem : rb + 16384;
    sb = (sb == smem + 2 * 16384) ? smem : sb + 16384;
  }
  asm volatile("s_waitcnt vmcnt(0)\n\ts_barrier" ::: "memory");
  G64_COMPUTE;

  const int j = n0 + w * 16 + cl;
  const float bj = bias[j];
#pragma unroll
  for (int mi = 0; mi < 4; ++mi)
#pragma unroll
    for (int r = 0; r < 4; ++r) {
      const int row = m0 + mi * 16 + q * 4 + r;
      float v = acc[mi][r] + bj;
      if (mode == 0) {
        v = fmaxf(v, 0.f);
        const int b = row >> 1, l = row & 1;   // x rows are (b, l) pairs
        if (l == 0) { o0f[(long)b * HD + j] = v; o0b[(long)b * HD + j] = __float2bfloat16(v); }
        else        { o1f[(long)b * HD + j] = v; o1b[(long)b * HD + j] = __float2bfloat16(v); }
      } else {
        preds[((long)row * TT + t) * OD + j] = v;
        xbuf[(long)row * OD + j] = __float2bfloat16(v);
      }
    }
}

// ---- naive fallbacks (only if workspace too small for bf16 weights) ----
__global__ __launch_bounds__(256) void gru_cell_naive(
    const bf16* __restrict__ Ax, int Kx, const bf16* __restrict__ Ahb,
    const float* __restrict__ hprevf,
    const float* __restrict__ Wih, const float* __restrict__ Whh,
    const float* __restrict__ bih, const float* __restrict__ bhh,
    float* __restrict__ houtf, bf16* __restrict__ houtb) {
  const int idx = blockIdx.x * 256 + threadIdx.x;
  if (idx >= BB * HD) return;
  const int b = idx / HD, j = idx % HD;
  float gr = bih[j] + bhh[j], gz = bih[j + HD] + bhh[j + HD];
  float gnx = bih[j + 2 * HD], gnh = bhh[j + 2 * HD];
  for (int k = 0; k < Kx; ++k) {
    const float xv = __bfloat162float(Ax[(long)b * Kx + k]);
    gr += xv * Wih[(long)j * Kx + k];
    gz += xv * Wih[((long)j + HD) * Kx + k];
    gnx += xv * Wih[((long)j + 2 * HD) * Kx + k];
  }
  for (int k = 0; k < HD; ++k) {
    const float hv = __bfloat162float(Ahb[(long)b * HD + k]);
    gr += hv * Whh[(long)j * HD + k];
    gz += hv * Whh[((long)j + HD) * HD + k];
    gnh += hv * Whh[((long)j + 2 * HD) * HD + k];
  }
  const float rr = 1.f / (1.f + __expf(-gr));
  const float zz = 1.f / (1.f + __expf(-gz));
  const float nn = tanhf(gnx + rr * gnh);
  const float hp = hprevf[(long)b * HD + j];
  const float hn = (1.f - zz) * nn + zz * hp;
  houtf[(long)b * HD + j] = hn;
  houtb[(long)b * HD + j] = __float2bfloat16(hn);
}

__global__ __launch_bounds__(256) void naive_gemm(
    const void* __restrict__ A, int abf, const float* __restrict__ W,
    const float* __restrict__ bias, int N, int K, int mode, int t,
    float* __restrict__ o0f, bf16* __restrict__ o0b,
    float* __restrict__ o1f, bf16* __restrict__ o1b,
    float* __restrict__ preds, bf16* __restrict__ xbuf) {
  const long idx = (long)blockIdx.x * 256 + threadIdx.x;
  const int row = idx / N, j = idx % N;
  float v = bias[j];
  for (int k = 0; k < K; ++k) {
    const float av = abf ? __bfloat162float(((const bf16*)A)[(long)row * K + k])
                         : ((const float*)A)[(long)row * K + k];
    v += av * W[(long)j * K + k];
  }
  if (mode == 0) {
    v = fmaxf(v, 0.f);
    const int b = row >> 1, l = row & 1;
    if (l == 0) { o0f[(long)b * HD + j] = v; o0b[(long)b * HD + j] = __float2bfloat16(v); }
    else        { o1f[(long)b * HD + j] = v; o1b[(long)b * HD + j] = __float2bfloat16(v); }
  } else {
    preds[((long)row * TT + t) * OD + j] = v;
    xbuf[(long)row * OD + j] = __float2bfloat16(v);
  }
}

extern "C" void kernel_launch(void* const* d_in, const int* in_sizes, int n_in,
                              void* d_out, int out_size, void* d_ws, size_t ws_size,
                              hipStream_t stream) {
  const float* x    = (const float*)d_in[0];
  const float* embW = (const float*)d_in[1];
  const float* embb = (const float*)d_in[2];
  const float* Wih0 = (const float*)d_in[3];
  const float* Whh0 = (const float*)d_in[4];
  const float* bih0 = (const float*)d_in[5];
  const float* bhh0 = (const float*)d_in[6];
  const float* Wih1 = (const float*)d_in[7];
  const float* Whh1 = (const float*)d_in[8];
  const float* bih1 = (const float*)d_in[9];
  const float* bhh1 = (const float*)d_in[10];
  const float* outW = (const float*)d_in[11];
  const float* outb = (const float*)d_in[12];
  float* preds = (float*)d_out;

  char* p = (char*)d_ws;
  const size_t HF = (size_t)BB * HD * 4;
  const size_t HB = (size_t)BB * HD * 2;
  float* h0f[2] = {(float*)p, (float*)(p + HF)}; p += 2 * HF;
  float* h1f[2] = {(float*)p, (float*)(p + HF)}; p += 2 * HF;
  bf16* h0b[2] = {(bf16*)p, (bf16*)(p + HB)}; p += 2 * HB;
  bf16* h1b[2] = {(bf16*)p, (bf16*)(p + HB)}; p += 2 * HB;
  bf16* xbuf = (bf16*)p; p += (size_t)BB * OD * 2;

  const int nE = 2048 * 1024, nI0 = 6144 * 512, nH = 6144 * 2048,
            nO = 512 * 2048, nX = 1024 * 1024;
  const size_t conv_bytes = 2ul * (nE + nI0 + 3ul * nH + nO + nX);
  const bool big = ws_size >= (size_t)(p - (char*)d_ws) + conv_bytes;

  hipMemsetAsync(xbuf, 0, (size_t)BB * OD * 2, stream);  // zero input, steps 0-1

  if (big) {
    bf16* embWc = (bf16*)p; p += 2ul * nE;
    bf16* Wih0c = (bf16*)p; p += 2ul * nI0;
    bf16* Whh0c = (bf16*)p; p += 2ul * nH;
    bf16* Wih1c = (bf16*)p; p += 2ul * nH;
    bf16* Whh1c = (bf16*)p; p += 2ul * nH;
    bf16* outWc = (bf16*)p; p += 2ul * nO;
    bf16* xbf   = (bf16*)p; p += 2ul * nX;
    auto cv = [&](const float* s, bf16* d, int n) {
      cvt_kernel<<<(n / 4 + 255) / 256, 256, 0, stream>>>(s, d, n / 4);
    };
    cv(embW, embWc, nE); cv(Wih0, Wih0c, nI0); cv(Whh0, Whh0c, nH);
    cv(Wih1, Wih1c, nH); cv(Whh1, Whh1c, nH); cv(outW, outWc, nO);
    cv(x, xbf, nX);

    // embedding: xbf [1024,1024] -> h0/h1; 16 m-tiles x 32 n-tiles
    gemm64_kernel<<<512, 256, 0, stream>>>(
        xbf, embWc, embb, 1024, 0, 0, 2,
        h0f[0], h0b[0], h1f[0], h1b[0], nullptr, nullptr);

    for (int s = 0; s < 33; ++s) {
      const int cur = s & 1, nxt = cur ^ 1;
      gru_cell_kernel<<<512, 256, 0, stream>>>(
          xbuf, OD, h0b[cur], h0f[cur], Wih0c, Whh0c, bih0, bhh0,
          h0f[nxt], h0b[nxt]);
      gru_cell_kernel<<<512, 256, 0, stream>>>(
          h0b[nxt], HD, h1b[cur], h1f[cur], Wih1c, Whh1c, bih1, bhh1,
          h1f[nxt], h1b[nxt]);
      if (s >= 1)
        gemm64_kernel<<<64, 256, 0, stream>>>(
            h1b[nxt], outWc, outb, HD, 1, s - 1, 0,
            nullptr, nullptr, nullptr, nullptr, preds, xbuf);
    }
  } else {
    naive_gemm<<<(1024 * 2048) / 256, 256, 0, stream>>>(
        x, 0, embW, embb, 2048, 1024, 0, 0,
        h0f[0], h0b[0], h1f[0], h1b[0], nullptr, nullptr);
    for (int s = 0; s < 33; ++s) {
      const int cur = s & 1, nxt = cur ^ 1;
      gru_cell_naive<<<(BB * HD + 255) / 256, 256, 0, stream>>>(
          xbuf, OD, h0b[cur], h0f[cur], Wih0, Whh0, bih0, bhh0,
          h0f[nxt], h0b[nxt]);
      gru_cell_naive<<<(BB * HD + 255) / 256, 256, 0, stream>>>(
          h0b[nxt], HD, h1b[cur], h1f[cur], Wih1, Whh1, bih1, bhh1,
          h1f[nxt], h1b[nxt]);
      if (s >= 1)
        naive_gemm<<<(512 * 512) / 256, 256, 0, stream>>>(
            h1b[nxt], 1, outW, outb, 512, 2048, 1, s - 1,
            nullptr, nullptr, nullptr, nullptr, preds, xbuf);
    }
  }
}